// Round 14
// baseline (949.026 us; speedup 1.0000x reference)
//
#include <hip/hip_runtime.h>
#include <hip/hip_bf16.h>

// SGC: out = A'^2 X W^T + b, A' = D^-1/2 (A+I) D^-1/2, A_data == 1.
// Identity: A'(A'(X W^T)) = (A'^2 X) W^T -> project 128->64 FIRST, propagate 64-dim.
//   xp = is * bf16(X) bf16(W)^T;  z1 = is^2 (A+I) xp;  out = is (A+I) z1 + b
// R13 audit: ~85us of the 193us wall was launch/gap overhead (6 dispatches).
// => 3 dispatches: memset; build(bucket->bar->csr->bar->proj, 768 blocks,
// 4/CU capacity); spmm(layer1->bar->layer2, 1792 blocks, 8/CU capacity,
// 28 waves/CU — MORE TLP than R10's standalone spmm, fixing R12's mistake of
// one grid for all phases). Software grid barriers: device-scope atomic +
// threadfence; co-residency guaranteed by launch_bounds + LDS margin.

#define NFEAT 128
#define NCLS  64
#define BCAP  9216     // bucket cap; Poisson(8163) -> +11.6 sigma
#define T1    16       // edges per thread, bucket phase
#define XSTR  136      // W staged row stride in bf16 elems
#define GB    768      // build grid: capacity 4/CU*256=1024 (LDS 38KB, VGPR<=128)
#define GS    1792     // spmm grid: capacity 8/CU*256=2048 (LDS 0, VGPR<=64)

typedef __attribute__((ext_vector_type(8))) short s16x8;   // 8 bf16 = 4 VGPRs
typedef __attribute__((ext_vector_type(4))) float f32x4;   // MFMA C/D

static __device__ __forceinline__ unsigned short f2bf(float f) {
    __hip_bfloat16 h = __float2bfloat16(f);
    unsigned short u;
    __builtin_memcpy(&u, &h, 2);
    return u;
}

static __device__ __forceinline__ float bf2f(unsigned short u) {
    unsigned int w = ((unsigned int)u) << 16;
    float f;
    __builtin_memcpy(&f, &w, 4);
    return f;
}

// software grid barrier: all blocks co-resident (guaranteed by grid<=capacity).
// release: threadfence + device-scope atomicAdd; acquire: agent-scope load + fence.
static __device__ __forceinline__ void grid_barrier(int* cnt, int nblk) {
    __syncthreads();
    if (threadIdx.x == 0) {
        __threadfence();
        atomicAdd(cnt, 1);
        while (__hip_atomic_load(cnt, __ATOMIC_ACQUIRE, __HIP_MEMORY_SCOPE_AGENT) < nblk)
            __builtin_amdgcn_s_sleep(8);
        __threadfence();
    }
    __syncthreads();
}

// ---------------- dispatch 2: bucket -> csr -> proj ----------------

__global__ __launch_bounds__(256, 4)
void build_kernel(const float* __restrict__ x, const int2* __restrict__ idx,
                  const float* __restrict__ W,
                  int* __restrict__ bcur, int* __restrict__ bar,
                  int* __restrict__ bpack, int* __restrict__ csr,
                  int2* __restrict__ rowinfo, unsigned short* __restrict__ xp,
                  int n, int E, int nb, int nchunks, int ntiles) {
    __shared__ __align__(16) char smem[38912];
    int tid = threadIdx.x;
    int lane = tid & 63;

    // ---- phase 1: bucket split (row>>8), packed (row&255)<<24 | col ----
    {
        int*   hist   = (int*)smem;              // 1 KB
        int*   base   = (int*)(smem + 1024);     // 1 KB
        int*   packed = (int*)(smem + 2048);     // 16 KB
        short* digit  = (short*)(smem + 18432);  // 8 KB
        for (int chunk = blockIdx.x; chunk < nchunks; chunk += gridDim.x) {
            hist[tid] = 0;
            __syncthreads();
            int e0 = chunk * 256 * T1;
#pragma unroll
            for (int k = 0; k < T1; ++k) {
                int e = e0 + k * 256 + tid;
                int s = k * 256 + tid;
                if (e < E) {
                    int2 rc = idx[e];
                    int d = rc.x >> 8;
                    digit[s] = (short)d;
                    packed[s] = ((rc.x & 255) << 24) | rc.y;
                    atomicAdd(&hist[d], 1);                     // LDS atomic
                } else {
                    digit[s] = -1;
                }
            }
            __syncthreads();
            {
                int c = hist[tid];
                base[tid] = (c > 0) ? atomicAdd(&bcur[tid], c) : 0;  // 1 glob atomic/digit
                hist[tid] = 0;                                       // reuse as cursor
            }
            __syncthreads();
#pragma unroll
            for (int k = 0; k < T1; ++k) {
                int s = k * 256 + tid;
                int d = digit[s];
                if (d >= 0) {
                    int r = base[d] + atomicAdd(&hist[d], 1);   // LDS atomic
                    if (r < BCAP) bpack[d * BCAP + r] = packed[s];
                }
            }
            __syncthreads();   // protect hist reuse next chunk
        }
    }
    grid_barrier(&bar[0], gridDim.x);

    // ---- phase 2: per-bucket CSR (rowinfo + contiguous cols) ----
    {
        int* cnt   = (int*)smem;            // 1 KB
        int* wtot  = (int*)(smem + 1024);   // 16 B
        int* stage = (int*)(smem + 1040);   // 36 KB
        int wid = tid >> 6;
        for (int b = blockIdx.x; b < nb; b += gridDim.x) {
            int m = bcur[b]; if (m > BCAP) m = BCAP;
            const int* src = bpack + b * BCAP;
            cnt[tid] = 0;
            __syncthreads();
            for (int j = tid; j < m; j += 256) {
                int p = src[j];
                stage[j] = p;
                atomicAdd(&cnt[((unsigned)p) >> 24], 1);        // LDS atomic
            }
            __syncthreads();
            int v = cnt[tid], s = v;
#pragma unroll
            for (int off = 1; off < 64; off <<= 1) {
                int t = __shfl_up(s, off, 64);
                if (lane >= off) s += t;
            }
            if (lane == 63) wtot[wid] = s;
            __syncthreads();
            int wbase = 0;
#pragma unroll
            for (int w = 0; w < 4; ++w) { int t = wtot[w]; if (w < wid) wbase += t; }
            int excl = wbase + s - v;
            int row = (b << 8) + tid;
            int csrbase = b * BCAP;
            if (row < n) rowinfo[row] = make_int2(csrbase + excl, v);
            __syncthreads();
            cnt[tid] = excl;              // reuse as write cursors
            __syncthreads();
            for (int j = tid; j < m; j += 256) {
                int p = stage[j];
                unsigned d = ((unsigned)p) >> 24;
                int r = atomicAdd(&cnt[d], 1);                  // LDS atomic
                csr[csrbase + r] = p & 0xFFFFFF;
            }
            __syncthreads();   // protect cnt reuse next bucket
        }
    }
    grid_barrier(&bar[1], gridDim.x);

    // ---- phase 3: proj (MFMA 16x16x32): xp = is * bf16(X) bf16(W)^T ----
    // A from global (in-reg cvt), B from LDS. D: col=lane&15, row=q*4+reg.
    {
        unsigned short* Ws = (unsigned short*)smem;   // 17 KB
        int wv = tid >> 6;
        int mn = lane & 15, q = lane >> 4;
        for (int g = tid; g < 2048; g += 256) {       // 64 cls x 32 float4-granules
            int r = g >> 5, c4 = g & 31;
            float4 v = *(const float4*)&W[r * NFEAT + 4 * c4];
            ushort4 o = { f2bf(v.x), f2bf(v.y), f2bf(v.z), f2bf(v.w) };
            *(ushort4*)&Ws[r * XSTR + 4 * c4] = o;
        }
        __syncthreads();

        for (int tile = blockIdx.x; tile < ntiles; tile += gridDim.x) {
            int row0 = tile * 64;
            int arow = row0 + 16 * wv + mn;
            if (arow >= n) arow = n - 1;
            const float* xr = &x[(size_t)arow * NFEAT];

            f32x4 z = { 0.0f, 0.0f, 0.0f, 0.0f };
            f32x4 acc[4] = { z, z, z, z };
#pragma unroll
            for (int kk = 0; kk < 4; ++kk) {          // K = 4 x 32
                float4 a0 = *(const float4*)&xr[kk * 32 + q * 8];
                float4 a1 = *(const float4*)&xr[kk * 32 + q * 8 + 4];
                unsigned short ab[8] = { f2bf(a0.x), f2bf(a0.y), f2bf(a0.z), f2bf(a0.w),
                                         f2bf(a1.x), f2bf(a1.y), f2bf(a1.z), f2bf(a1.w) };
                s16x8 a;
                __builtin_memcpy(&a, ab, 16);
#pragma unroll
                for (int t = 0; t < 4; ++t) {
                    s16x8 b = *(const s16x8*)&Ws[(16 * t + mn) * XSTR + kk * 32 + q * 8];
                    acc[t] = __builtin_amdgcn_mfma_f32_16x16x32_bf16(a, b, acc[t], 0, 0, 0);
                }
            }
#pragma unroll
            for (int r = 0; r < 4; ++r) {
                int rr = row0 + 16 * wv + 4 * q + r;
                if (rr < n) {
                    float is = rsqrtf(1.0f + (float)rowinfo[rr].y);
#pragma unroll
                    for (int t = 0; t < 4; ++t)
                        xp[rr * NCLS + 16 * t + mn] = f2bf(acc[t][r] * is);
                }
            }
        }
    }
}

// ---------------- dispatch 3: SpMM x2 (layer1 -> barrier -> layer2) ----------------
// wave per row (grid-stride), quarter-wave pairing: f=lane&15 -> feats 4f..4f+3
// (ushort4), h=lane>>4 -> edge j+h. Reduce shfl_xor(16,32); h==0 writes.

__global__ __launch_bounds__(256, 8)
void spmm2_kernel(const ushort4* __restrict__ xp, unsigned short* __restrict__ z1,
                  const int2* __restrict__ rowinfo, const int* __restrict__ csr,
                  const float* __restrict__ bias, float* __restrict__ out,
                  int* __restrict__ bar, int n) {
    int tid = threadIdx.x;
    int lane = tid & 63;
    int h = lane >> 4, f = lane & 15;
    int gw = blockIdx.x * 4 + (tid >> 6);
    int nw = gridDim.x * 4;

#pragma unroll 1
    for (int layer = 0; layer < 2; ++layer) {
        const ushort4* src = (layer == 0) ? xp : (const ushort4*)z1;
        for (int row = gw; row < n; row += nw) {
            int2 ri = rowinfo[row];
            int m = ri.y;
            float is = rsqrtf(1.0f + (float)m);
            const int* eb = csr + ri.x;

            float4 acc = { 0.0f, 0.0f, 0.0f, 0.0f };
            if (h == 0) {                                   // self loop
                ushort4 s = src[(row << 4) + f];
                acc.x = bf2f(s.x); acc.y = bf2f(s.y); acc.z = bf2f(s.z); acc.w = bf2f(s.w);
            }

            int j = 0;
            for (; j + 32 <= m; j += 32) {                  // 8 gather insts in flight
                int c0 = eb[j + h],      c1 = eb[j + 4 + h];
                int c2 = eb[j + 8 + h],  c3 = eb[j + 12 + h];
                int c4 = eb[j + 16 + h], c5 = eb[j + 20 + h];
                int c6 = eb[j + 24 + h], c7 = eb[j + 28 + h];
                ushort4 g0 = src[(c0 << 4) + f];
                ushort4 g1 = src[(c1 << 4) + f];
                ushort4 g2 = src[(c2 << 4) + f];
                ushort4 g3 = src[(c3 << 4) + f];
                ushort4 g4 = src[(c4 << 4) + f];
                ushort4 g5 = src[(c5 << 4) + f];
                ushort4 g6 = src[(c6 << 4) + f];
                ushort4 g7 = src[(c7 << 4) + f];
                acc.x += bf2f(g0.x); acc.y += bf2f(g0.y); acc.z += bf2f(g0.z); acc.w += bf2f(g0.w);
                acc.x += bf2f(g1.x); acc.y += bf2f(g1.y); acc.z += bf2f(g1.z); acc.w += bf2f(g1.w);
                acc.x += bf2f(g2.x); acc.y += bf2f(g2.y); acc.z += bf2f(g2.z); acc.w += bf2f(g2.w);
                acc.x += bf2f(g3.x); acc.y += bf2f(g3.y); acc.z += bf2f(g3.z); acc.w += bf2f(g3.w);
                acc.x += bf2f(g4.x); acc.y += bf2f(g4.y); acc.z += bf2f(g4.z); acc.w += bf2f(g4.w);
                acc.x += bf2f(g5.x); acc.y += bf2f(g5.y); acc.z += bf2f(g5.z); acc.w += bf2f(g5.w);
                acc.x += bf2f(g6.x); acc.y += bf2f(g6.y); acc.z += bf2f(g6.z); acc.w += bf2f(g6.w);
                acc.x += bf2f(g7.x); acc.y += bf2f(g7.y); acc.z += bf2f(g7.z); acc.w += bf2f(g7.w);
            }
            for (; j + 8 <= m; j += 8) {
                int c0 = eb[j + h], c1 = eb[j + 4 + h];
                ushort4 g0 = src[(c0 << 4) + f];
                ushort4 g1 = src[(c1 << 4) + f];
                acc.x += bf2f(g0.x); acc.y += bf2f(g0.y); acc.z += bf2f(g0.z); acc.w += bf2f(g0.w);
                acc.x += bf2f(g1.x); acc.y += bf2f(g1.y); acc.z += bf2f(g1.z); acc.w += bf2f(g1.w);
            }
            for (; j < m; j += 4) {
                if (j + h < m) {
                    int c = eb[j + h];
                    ushort4 g = src[(c << 4) + f];
                    acc.x += bf2f(g.x); acc.y += bf2f(g.y); acc.z += bf2f(g.z); acc.w += bf2f(g.w);
                }
            }

            acc.x += __shfl_xor(acc.x, 16); acc.y += __shfl_xor(acc.y, 16);
            acc.z += __shfl_xor(acc.z, 16); acc.w += __shfl_xor(acc.w, 16);
            acc.x += __shfl_xor(acc.x, 32); acc.y += __shfl_xor(acc.y, 32);
            acc.z += __shfl_xor(acc.z, 32); acc.w += __shfl_xor(acc.w, 32);

            if (h == 0) {
                if (layer == 1) {
                    float4 b = *(const float4*)&bias[4 * f];
                    float4 o = { acc.x * is + b.x, acc.y * is + b.y,
                                 acc.z * is + b.z, acc.w * is + b.w };
                    ((float4*)out)[(row << 4) + f] = o;
                } else {
                    float sc = is * is;
                    ushort4 o = { f2bf(acc.x * sc), f2bf(acc.y * sc),
                                  f2bf(acc.z * sc), f2bf(acc.w * sc) };
                    ((ushort4*)z1)[(row << 4) + f] = o;
                }
            }
        }
        if (layer == 0) grid_barrier(&bar[2], gridDim.x);
    }
}

// ---------------- launch ----------------

extern "C" void kernel_launch(void* const* d_in, const int* in_sizes, int n_in,
                              void* d_out, int out_size, void* d_ws, size_t ws_size,
                              hipStream_t stream) {
    const float* X     = (const float*)d_in[0];
    const int2*  Aidx  = (const int2*)d_in[2];
    const float* W     = (const float*)d_in[3];
    const float* bias  = (const float*)d_in[4];
    float*       out   = (float*)d_out;

    const int n = in_sizes[0] / NFEAT;   // 50000
    const int E = in_sizes[1];           // 1600000
    const int nb = (n + 255) >> 8;       // 196 buckets
    const int nchunks = (E + 256 * T1 - 1) / (256 * T1);   // 391
    const int ntiles  = (n + 63) / 64;                     // 782

    char* ws = (char*)d_ws;
    size_t o = 0;
    auto alloc = [&](size_t bytes) { void* p = ws + o; o += (bytes + 255) & ~(size_t)255; return p; };
    int*  bcur    = (int*) alloc((nb + 8) * sizeof(int));            // bcur + barrier counters
    int*  bar     = bcur + nb;
    int*  bpack   = (int*) alloc((size_t)nb * BCAP * sizeof(int));   // 7.2 MB
    int*  csr     = (int*) alloc((size_t)nb * BCAP * sizeof(int));   // 7.2 MB
    int2* rowinfo = (int2*)alloc((size_t)n * sizeof(int2));          // 0.4 MB
    unsigned short* xp = (unsigned short*)alloc((size_t)n * NCLS * sizeof(unsigned short)); // 6.4 MB
    unsigned short* z1 = (unsigned short*)alloc((size_t)n * NCLS * sizeof(unsigned short)); // 6.4 MB

    hipMemsetAsync(bcur, 0, (nb + 8) * sizeof(int), stream);
    build_kernel<<<GB, 256, 0, stream>>>(X, Aidx, W, bcur, bar, bpack, csr,
                                         rowinfo, xp, n, E, nb, nchunks, ntiles);
    spmm2_kernel<<<GS, 256, 0, stream>>>((const ushort4*)xp, z1, rowinfo, csr,
                                         bias, out, bar, n);
}

// Round 15
// 581.219 us; speedup vs baseline: 1.6328x; 1.6328x over previous
//
#include <hip/hip_runtime.h>
#include <hip/hip_bf16.h>

// SGC: out = A'^2 X W^T + b, A' = D^-1/2 (A+I) D^-1/2, A_data == 1.
// Identity: A'(A'(X W^T)) = (A'^2 X) W^T -> project 128->64 FIRST, propagate 64-dim.
//   xp = is * bf16(X) bf16(W)^T;  z1 = is^2 (A+I) xp;  out = is (A+I) z1 + b
// 3 dispatches: memset; build(bucket->bar->csr->bar->proj, 768 blocks, 4/CU);
// spmm(layer1->bar->layer2, 1792 blocks, 8/CU = 28 waves/CU TLP).
// R14 post-mortem: barrier polled with ACQUIRE atomic loads -> buffer_inv per
// poll -> idle blocks continuously invalidated all 8 XCD L2s -> 949us. Fix:
// RELAXED polls + single threadfence after exit; bar[] on its own cache lines.

#define NFEAT 128
#define NCLS  64
#define BCAP  9216     // bucket cap; Poisson(8163) -> +11.6 sigma
#define T1    16       // edges per thread, bucket phase
#define XSTR  136      // W staged row stride in bf16 elems
#define GB    768      // build grid: capacity 4/CU*256=1024 (LDS 38KB, VGPR<=128)
#define GS    1792     // spmm grid: capacity 8/CU*256=2048 (LDS 0, VGPR<=64)

typedef __attribute__((ext_vector_type(8))) short s16x8;   // 8 bf16 = 4 VGPRs
typedef __attribute__((ext_vector_type(4))) float f32x4;   // MFMA C/D

static __device__ __forceinline__ unsigned short f2bf(float f) {
    __hip_bfloat16 h = __float2bfloat16(f);
    unsigned short u;
    __builtin_memcpy(&u, &h, 2);
    return u;
}

static __device__ __forceinline__ float bf2f(unsigned short u) {
    unsigned int w = ((unsigned int)u) << 16;
    float f;
    __builtin_memcpy(&f, &w, 4);
    return f;
}

// software grid barrier, co-residency guaranteed by grid <= capacity.
// Release: threadfence (one L2 writeback) + device-scope add.
// Poll: RELAXED loads (no cache invalidation!) + s_sleep.
// Acquire: ONE threadfence after the loop exits.
static __device__ __forceinline__ void grid_barrier(int* cnt, int nblk) {
    __syncthreads();
    if (threadIdx.x == 0) {
        __threadfence();
        __hip_atomic_fetch_add(cnt, 1, __ATOMIC_RELAXED, __HIP_MEMORY_SCOPE_AGENT);
        while (__hip_atomic_load(cnt, __ATOMIC_RELAXED, __HIP_MEMORY_SCOPE_AGENT) < nblk)
            __builtin_amdgcn_s_sleep(64);
        __threadfence();
    }
    __syncthreads();
}

// ---------------- dispatch 2: bucket -> csr -> proj ----------------

__global__ __launch_bounds__(256, 4)
void build_kernel(const float* __restrict__ x, const int2* __restrict__ idx,
                  const float* __restrict__ W,
                  int* __restrict__ bcur, int* __restrict__ bar,
                  int* __restrict__ bpack, int* __restrict__ csr,
                  int2* __restrict__ rowinfo, unsigned short* __restrict__ xp,
                  int n, int E, int nb, int nchunks, int ntiles) {
    __shared__ __align__(16) char smem[38912];
    int tid = threadIdx.x;
    int lane = tid & 63;

    // ---- phase 1: bucket split (row>>8), packed (row&255)<<24 | col ----
    {
        int*   hist   = (int*)smem;              // 1 KB
        int*   base   = (int*)(smem + 1024);     // 1 KB
        int*   packed = (int*)(smem + 2048);     // 16 KB
        short* digit  = (short*)(smem + 18432);  // 8 KB
        for (int chunk = blockIdx.x; chunk < nchunks; chunk += gridDim.x) {
            hist[tid] = 0;
            __syncthreads();
            int e0 = chunk * 256 * T1;
#pragma unroll
            for (int k = 0; k < T1; ++k) {
                int e = e0 + k * 256 + tid;
                int s = k * 256 + tid;
                if (e < E) {
                    int2 rc = idx[e];
                    int d = rc.x >> 8;
                    digit[s] = (short)d;
                    packed[s] = ((rc.x & 255) << 24) | rc.y;
                    atomicAdd(&hist[d], 1);                     // LDS atomic
                } else {
                    digit[s] = -1;
                }
            }
            __syncthreads();
            {
                int c = hist[tid];
                base[tid] = (c > 0) ? atomicAdd(&bcur[tid], c) : 0;  // 1 glob atomic/digit
                hist[tid] = 0;                                       // reuse as cursor
            }
            __syncthreads();
#pragma unroll
            for (int k = 0; k < T1; ++k) {
                int s = k * 256 + tid;
                int d = digit[s];
                if (d >= 0) {
                    int r = base[d] + atomicAdd(&hist[d], 1);   // LDS atomic
                    if (r < BCAP) bpack[d * BCAP + r] = packed[s];
                }
            }
            __syncthreads();   // protect hist reuse next chunk
        }
    }
    grid_barrier(&bar[0], gridDim.x);

    // ---- phase 2: per-bucket CSR (rowinfo + contiguous cols) ----
    {
        int* cnt   = (int*)smem;            // 1 KB
        int* wtot  = (int*)(smem + 1024);   // 16 B
        int* stage = (int*)(smem + 1040);   // 36 KB
        int wid = tid >> 6;
        for (int b = blockIdx.x; b < nb; b += gridDim.x) {
            int m = bcur[b]; if (m > BCAP) m = BCAP;
            const int* src = bpack + b * BCAP;
            cnt[tid] = 0;
            __syncthreads();
            for (int j = tid; j < m; j += 256) {
                int p = src[j];
                stage[j] = p;
                atomicAdd(&cnt[((unsigned)p) >> 24], 1);        // LDS atomic
            }
            __syncthreads();
            int v = cnt[tid], s = v;
#pragma unroll
            for (int off = 1; off < 64; off <<= 1) {
                int t = __shfl_up(s, off, 64);
                if (lane >= off) s += t;
            }
            if (lane == 63) wtot[wid] = s;
            __syncthreads();
            int wbase = 0;
#pragma unroll
            for (int w = 0; w < 4; ++w) { int t = wtot[w]; if (w < wid) wbase += t; }
            int excl = wbase + s - v;
            int row = (b << 8) + tid;
            int csrbase = b * BCAP;
            if (row < n) rowinfo[row] = make_int2(csrbase + excl, v);
            __syncthreads();
            cnt[tid] = excl;              // reuse as write cursors
            __syncthreads();
            for (int j = tid; j < m; j += 256) {
                int p = stage[j];
                unsigned d = ((unsigned)p) >> 24;
                int r = atomicAdd(&cnt[d], 1);                  // LDS atomic
                csr[csrbase + r] = p & 0xFFFFFF;
            }
            __syncthreads();   // protect cnt reuse next bucket
        }
    }
    grid_barrier(&bar[16], gridDim.x);

    // ---- phase 3: proj (MFMA 16x16x32): xp = is * bf16(X) bf16(W)^T ----
    // A from global (in-reg cvt), B from LDS. D: col=lane&15, row=q*4+reg.
    {
        unsigned short* Ws = (unsigned short*)smem;   // 17 KB
        int wv = tid >> 6;
        int mn = lane & 15, q = lane >> 4;
        for (int g = tid; g < 2048; g += 256) {       // 64 cls x 32 float4-granules
            int r = g >> 5, c4 = g & 31;
            float4 v = *(const float4*)&W[r * NFEAT + 4 * c4];
            ushort4 o = { f2bf(v.x), f2bf(v.y), f2bf(v.z), f2bf(v.w) };
            *(ushort4*)&Ws[r * XSTR + 4 * c4] = o;
        }
        __syncthreads();

        for (int tile = blockIdx.x; tile < ntiles; tile += gridDim.x) {
            int row0 = tile * 64;
            int arow = row0 + 16 * wv + mn;
            if (arow >= n) arow = n - 1;
            const float* xr = &x[(size_t)arow * NFEAT];

            f32x4 z = { 0.0f, 0.0f, 0.0f, 0.0f };
            f32x4 acc[4] = { z, z, z, z };
#pragma unroll
            for (int kk = 0; kk < 4; ++kk) {          // K = 4 x 32
                float4 a0 = *(const float4*)&xr[kk * 32 + q * 8];
                float4 a1 = *(const float4*)&xr[kk * 32 + q * 8 + 4];
                unsigned short ab[8] = { f2bf(a0.x), f2bf(a0.y), f2bf(a0.z), f2bf(a0.w),
                                         f2bf(a1.x), f2bf(a1.y), f2bf(a1.z), f2bf(a1.w) };
                s16x8 a;
                __builtin_memcpy(&a, ab, 16);
#pragma unroll
                for (int t = 0; t < 4; ++t) {
                    s16x8 b = *(const s16x8*)&Ws[(16 * t + mn) * XSTR + kk * 32 + q * 8];
                    acc[t] = __builtin_amdgcn_mfma_f32_16x16x32_bf16(a, b, acc[t], 0, 0, 0);
                }
            }
#pragma unroll
            for (int r = 0; r < 4; ++r) {
                int rr = row0 + 16 * wv + 4 * q + r;
                if (rr < n) {
                    float is = rsqrtf(1.0f + (float)rowinfo[rr].y);
#pragma unroll
                    for (int t = 0; t < 4; ++t)
                        xp[rr * NCLS + 16 * t + mn] = f2bf(acc[t][r] * is);
                }
            }
        }
    }
}

// ---------------- dispatch 3: SpMM x2 (layer1 -> barrier -> layer2) ----------------
// wave per row (grid-stride), quarter-wave pairing: f=lane&15 -> feats 4f..4f+3
// (ushort4), h=lane>>4 -> edge j+h. Reduce shfl_xor(16,32); h==0 writes.

__global__ __launch_bounds__(256, 8)
void spmm2_kernel(const ushort4* __restrict__ xp, unsigned short* __restrict__ z1,
                  const int2* __restrict__ rowinfo, const int* __restrict__ csr,
                  const float* __restrict__ bias, float* __restrict__ out,
                  int* __restrict__ bar, int n) {
    int tid = threadIdx.x;
    int lane = tid & 63;
    int h = lane >> 4, f = lane & 15;
    int gw = blockIdx.x * 4 + (tid >> 6);
    int nw = gridDim.x * 4;

#pragma unroll 1
    for (int layer = 0; layer < 2; ++layer) {
        const ushort4* src = (layer == 0) ? xp : (const ushort4*)z1;
        for (int row = gw; row < n; row += nw) {
            int2 ri = rowinfo[row];
            int m = ri.y;
            float is = rsqrtf(1.0f + (float)m);
            const int* eb = csr + ri.x;

            float4 acc = { 0.0f, 0.0f, 0.0f, 0.0f };
            if (h == 0) {                                   // self loop
                ushort4 s = src[(row << 4) + f];
                acc.x = bf2f(s.x); acc.y = bf2f(s.y); acc.z = bf2f(s.z); acc.w = bf2f(s.w);
            }

            int j = 0;
            for (; j + 32 <= m; j += 32) {                  // 8 gather insts in flight
                int c0 = eb[j + h],      c1 = eb[j + 4 + h];
                int c2 = eb[j + 8 + h],  c3 = eb[j + 12 + h];
                int c4 = eb[j + 16 + h], c5 = eb[j + 20 + h];
                int c6 = eb[j + 24 + h], c7 = eb[j + 28 + h];
                ushort4 g0 = src[(c0 << 4) + f];
                ushort4 g1 = src[(c1 << 4) + f];
                ushort4 g2 = src[(c2 << 4) + f];
                ushort4 g3 = src[(c3 << 4) + f];
                ushort4 g4 = src[(c4 << 4) + f];
                ushort4 g5 = src[(c5 << 4) + f];
                ushort4 g6 = src[(c6 << 4) + f];
                ushort4 g7 = src[(c7 << 4) + f];
                acc.x += bf2f(g0.x); acc.y += bf2f(g0.y); acc.z += bf2f(g0.z); acc.w += bf2f(g0.w);
                acc.x += bf2f(g1.x); acc.y += bf2f(g1.y); acc.z += bf2f(g1.z); acc.w += bf2f(g1.w);
                acc.x += bf2f(g2.x); acc.y += bf2f(g2.y); acc.z += bf2f(g2.z); acc.w += bf2f(g2.w);
                acc.x += bf2f(g3.x); acc.y += bf2f(g3.y); acc.z += bf2f(g3.z); acc.w += bf2f(g3.w);
                acc.x += bf2f(g4.x); acc.y += bf2f(g4.y); acc.z += bf2f(g4.z); acc.w += bf2f(g4.w);
                acc.x += bf2f(g5.x); acc.y += bf2f(g5.y); acc.z += bf2f(g5.z); acc.w += bf2f(g5.w);
                acc.x += bf2f(g6.x); acc.y += bf2f(g6.y); acc.z += bf2f(g6.z); acc.w += bf2f(g6.w);
                acc.x += bf2f(g7.x); acc.y += bf2f(g7.y); acc.z += bf2f(g7.z); acc.w += bf2f(g7.w);
            }
            for (; j + 8 <= m; j += 8) {
                int c0 = eb[j + h], c1 = eb[j + 4 + h];
                ushort4 g0 = src[(c0 << 4) + f];
                ushort4 g1 = src[(c1 << 4) + f];
                acc.x += bf2f(g0.x); acc.y += bf2f(g0.y); acc.z += bf2f(g0.z); acc.w += bf2f(g0.w);
                acc.x += bf2f(g1.x); acc.y += bf2f(g1.y); acc.z += bf2f(g1.z); acc.w += bf2f(g1.w);
            }
            for (; j < m; j += 4) {
                if (j + h < m) {
                    int c = eb[j + h];
                    ushort4 g = src[(c << 4) + f];
                    acc.x += bf2f(g.x); acc.y += bf2f(g.y); acc.z += bf2f(g.z); acc.w += bf2f(g.w);
                }
            }

            acc.x += __shfl_xor(acc.x, 16); acc.y += __shfl_xor(acc.y, 16);
            acc.z += __shfl_xor(acc.z, 16); acc.w += __shfl_xor(acc.w, 16);
            acc.x += __shfl_xor(acc.x, 32); acc.y += __shfl_xor(acc.y, 32);
            acc.z += __shfl_xor(acc.z, 32); acc.w += __shfl_xor(acc.w, 32);

            if (h == 0) {
                if (layer == 1) {
                    float4 b = *(const float4*)&bias[4 * f];
                    float4 o = { acc.x * is + b.x, acc.y * is + b.y,
                                 acc.z * is + b.z, acc.w * is + b.w };
                    ((float4*)out)[(row << 4) + f] = o;
                } else {
                    float sc = is * is;
                    ushort4 o = { f2bf(acc.x * sc), f2bf(acc.y * sc),
                                  f2bf(acc.z * sc), f2bf(acc.w * sc) };
                    ((ushort4*)z1)[(row << 4) + f] = o;
                }
            }
        }
        if (layer == 0) grid_barrier(&bar[32], gridDim.x);
    }
}

// ---------------- launch ----------------

extern "C" void kernel_launch(void* const* d_in, const int* in_sizes, int n_in,
                              void* d_out, int out_size, void* d_ws, size_t ws_size,
                              hipStream_t stream) {
    const float* X     = (const float*)d_in[0];
    const int2*  Aidx  = (const int2*)d_in[2];
    const float* W     = (const float*)d_in[3];
    const float* bias  = (const float*)d_in[4];
    float*       out   = (float*)d_out;

    const int n = in_sizes[0] / NFEAT;   // 50000
    const int E = in_sizes[1];           // 1600000
    const int nb = (n + 255) >> 8;       // 196 buckets
    const int nchunks = (E + 256 * T1 - 1) / (256 * T1);   // 391
    const int ntiles  = (n + 63) / 64;                     // 782

    char* ws = (char*)d_ws;
    size_t o = 0;
    auto alloc = [&](size_t bytes) { void* p = ws + o; o += (bytes + 255) & ~(size_t)255; return p; };
    int*  bcur    = (int*) alloc(nb * sizeof(int));
    int*  bar     = (int*) alloc(64 * sizeof(int));                  // own cache lines
    int*  bpack   = (int*) alloc((size_t)nb * BCAP * sizeof(int));   // 7.2 MB
    int*  csr     = (int*) alloc((size_t)nb * BCAP * sizeof(int));   // 7.2 MB
    int2* rowinfo = (int2*)alloc((size_t)n * sizeof(int2));          // 0.4 MB
    unsigned short* xp = (unsigned short*)alloc((size_t)n * NCLS * sizeof(unsigned short)); // 6.4 MB
    unsigned short* z1 = (unsigned short*)alloc((size_t)n * NCLS * sizeof(unsigned short)); // 6.4 MB

    hipMemsetAsync(bcur, 0, nb * sizeof(int), stream);
    hipMemsetAsync(bar, 0, 64 * sizeof(int), stream);
    build_kernel<<<GB, 256, 0, stream>>>(X, Aidx, W, bcur, bar, bpack, csr,
                                         rowinfo, xp, n, E, nb, nchunks, ntiles);
    spmm2_kernel<<<GS, 256, 0, stream>>>((const ushort4*)xp, z1, rowinfo, csr,
                                         bias, out, bar, n);
}

// Round 16
// 192.961 us; speedup vs baseline: 4.9182x; 3.0121x over previous
//
#include <hip/hip_runtime.h>
#include <hip/hip_bf16.h>

// SGC: out = A'^2 X W^T + b, A' = D^-1/2 (A+I) D^-1/2, A_data == 1.
// Identity: A'(A'(X W^T)) = (A'^2 X) W^T -> project 128->64 FIRST, propagate 64-dim.
//   xp = is * bf16(X) bf16(W)^T;  z1 = is^2 (A+I) xp;  out = is (A+I) z1 + b
// Structure: 5 dispatches — memset(bcur); bucket; csr+proj (merged: bucket b's
// block owns rows [256b,256b+256) end-to-end, so proj of those rows needs no
// cross-block data); spmm x2. Fusion-with-grid-barriers is ABANDONED: R12/R14/
// R15 all showed intra-kernel cross-XCD phase transitions cost 3-5x (SW fences
// + coherent polling degrade the whole memory system; HW kernel-boundary
// flushes are ~free). spmm is at the ~64G sectors/s request-rate wall
// (fp32 845MB/108us == bf16 211MB/50us in sector terms) — left as-is.

#define NFEAT 128
#define NCLS  64
#define BCAP  9216     // bucket cap; Poisson(8163) -> +11.6 sigma
#define T1    16       // edges per thread, bucket pass
#define XSTR  136      // W staged row stride in bf16 elems

typedef __attribute__((ext_vector_type(8))) short s16x8;   // 8 bf16 = 4 VGPRs
typedef __attribute__((ext_vector_type(4))) float f32x4;   // MFMA C/D

static __device__ __forceinline__ unsigned short f2bf(float f) {
    __hip_bfloat16 h = __float2bfloat16(f);
    unsigned short u;
    __builtin_memcpy(&u, &h, 2);
    return u;
}

static __device__ __forceinline__ float bf2f(unsigned short u) {
    unsigned int w = ((unsigned int)u) << 16;
    float f;
    __builtin_memcpy(&f, &w, 4);
    return f;
}

// ---------------- pass 1: bucket split (row>>8), packed (row&255)<<24 | col ----------------

__global__ __launch_bounds__(256) void bucket_kernel(const int2* __restrict__ idx,
                                                     int* __restrict__ bcur,
                                                     int* __restrict__ bpack, int E) {
    __shared__ int hist[256];
    __shared__ int base[256];
    __shared__ int packed[256 * T1];   // 16 KB
    __shared__ short digit[256 * T1];  // 8 KB
    int tid = threadIdx.x;
    hist[tid] = 0;
    __syncthreads();

    int e0 = blockIdx.x * 256 * T1;
#pragma unroll
    for (int k = 0; k < T1; ++k) {
        int e = e0 + k * 256 + tid;
        int s = k * 256 + tid;
        if (e < E) {
            int2 rc = idx[e];
            int d = rc.x >> 8;
            digit[s] = (short)d;
            packed[s] = ((rc.x & 255) << 24) | rc.y;
            atomicAdd(&hist[d], 1);                     // LDS atomic
        } else {
            digit[s] = -1;
        }
    }
    __syncthreads();
    {
        int c = hist[tid];
        base[tid] = (c > 0) ? atomicAdd(&bcur[tid], c) : 0; // 1 global atomic/digit/block
        hist[tid] = 0;                                      // reuse as cursor
    }
    __syncthreads();
#pragma unroll
    for (int k = 0; k < T1; ++k) {
        int s = k * 256 + tid;
        int d = digit[s];
        if (d >= 0) {
            int r = base[d] + atomicAdd(&hist[d], 1);   // LDS atomic
            if (r < BCAP) bpack[d * BCAP + r] = packed[s];
        }
    }
}

// ---------------- pass 2: per-bucket CSR + proj of the bucket's own 256 rows ----------------
// csr: LDS stage + histogram + shuffle scan -> rowinfo, contiguous cols.
// proj: same block then stages W (smem reused) and runs 4 MFMA 16x16x32 tiles
// for rows [256b, 256b+256): xp[r][c] = bf16( is_r * dot(X[r,:], W[c,:]) ).
// A from global (in-reg fp32->bf16 cvt); B from LDS; D: col=lane&15, row=q*4+reg.

__global__ __launch_bounds__(256) void csrproj_kernel(const int* __restrict__ bcur,
                                                      const int* __restrict__ bpack,
                                                      const float* __restrict__ x,
                                                      const float* __restrict__ W,
                                                      int* __restrict__ csr,
                                                      int2* __restrict__ rowinfo,
                                                      unsigned short* __restrict__ xp, int n) {
    __shared__ int cnt[256];
    __shared__ int wtot[4];
    __shared__ float isv[256];
    __shared__ __align__(16) char smem[BCAP * 4];   // 36 KB: stage, then Ws (17 KB)
    int* stage = (int*)smem;
    unsigned short* Ws = (unsigned short*)smem;

    int b = blockIdx.x, tid = threadIdx.x;
    int lane = tid & 63, wid = tid >> 6;
    int m = bcur[b]; if (m > BCAP) m = BCAP;
    const int* src = bpack + b * BCAP;

    cnt[tid] = 0;
    __syncthreads();
    for (int j = tid; j < m; j += 256) {
        int p = src[j];
        stage[j] = p;
        atomicAdd(&cnt[((unsigned)p) >> 24], 1);        // LDS atomic
    }
    __syncthreads();

    // exclusive scan of cnt[256]
    int v = cnt[tid], s = v;
#pragma unroll
    for (int off = 1; off < 64; off <<= 1) {
        int t = __shfl_up(s, off, 64);
        if (lane >= off) s += t;
    }
    if (lane == 63) wtot[wid] = s;
    __syncthreads();
    int wbase = 0;
#pragma unroll
    for (int w = 0; w < 4; ++w) { int t = wtot[w]; if (w < wid) wbase += t; }
    int excl = wbase + s - v;

    int row = (b << 8) + tid;
    int csrbase = b * BCAP;
    if (row < n) rowinfo[row] = make_int2(csrbase + excl, v);
    isv[tid] = rsqrtf(1.0f + (float)v);
    __syncthreads();              // counts consumed
    cnt[tid] = excl;              // reuse as write cursors
    __syncthreads();
    for (int j = tid; j < m; j += 256) {
        int p = stage[j];
        unsigned d = ((unsigned)p) >> 24;
        int r = atomicAdd(&cnt[d], 1);                  // LDS atomic
        csr[csrbase + r] = p & 0xFFFFFF;
    }
    __syncthreads();              // stage dead -> smem becomes Ws

    // ---- proj for this bucket's rows ----
    for (int g = tid; g < 2048; g += 256) {             // 64 cls x 32 float4-granules
        int r = g >> 5, c4 = g & 31;
        float4 vv = *(const float4*)&W[r * NFEAT + 4 * c4];
        ushort4 o = { f2bf(vv.x), f2bf(vv.y), f2bf(vv.z), f2bf(vv.w) };
        *(ushort4*)&Ws[r * XSTR + 4 * c4] = o;
    }
    __syncthreads();

    int wv = tid >> 6;
    int mn = lane & 15, q = lane >> 4;
#pragma unroll 1
    for (int t4 = 0; t4 < 4; ++t4) {                    // 4 tiles of 64 rows
        int row0 = (b << 8) + 64 * t4;
        if (row0 >= n) break;
        int arow = row0 + 16 * wv + mn;
        if (arow >= n) arow = n - 1;
        const float* xr = &x[(size_t)arow * NFEAT];

        f32x4 z = { 0.0f, 0.0f, 0.0f, 0.0f };
        f32x4 acc[4] = { z, z, z, z };
#pragma unroll
        for (int kk = 0; kk < 4; ++kk) {                // K = 4 x 32
            float4 a0 = *(const float4*)&xr[kk * 32 + q * 8];
            float4 a1 = *(const float4*)&xr[kk * 32 + q * 8 + 4];
            unsigned short ab[8] = { f2bf(a0.x), f2bf(a0.y), f2bf(a0.z), f2bf(a0.w),
                                     f2bf(a1.x), f2bf(a1.y), f2bf(a1.z), f2bf(a1.w) };
            s16x8 a;
            __builtin_memcpy(&a, ab, 16);
#pragma unroll
            for (int t = 0; t < 4; ++t) {
                s16x8 bb = *(const s16x8*)&Ws[(16 * t + mn) * XSTR + kk * 32 + q * 8];
                acc[t] = __builtin_amdgcn_mfma_f32_16x16x32_bf16(a, bb, acc[t], 0, 0, 0);
            }
        }
#pragma unroll
        for (int r = 0; r < 4; ++r) {
            int rr = row0 + 16 * wv + 4 * q + r;
            if (rr < n) {
                float is = isv[64 * t4 + 16 * wv + 4 * q + r];
#pragma unroll
                for (int t = 0; t < 4; ++t)
                    xp[rr * NCLS + 16 * t + mn] = f2bf(acc[t][r] * is);
            }
        }
    }
}

// ---------------- SpMM: wave per row, quarter-wave pairing ----------------
// lane: f = lane&15 covers feats 4f..4f+3 (ushort4, 8B), h = lane>>4 -> edge j+h.
// Sector-rate-bound (~64G 64B-sectors/s chip-wide): 2 sectors/edge is the floor.

template <int FINAL>
__global__ __launch_bounds__(256) void spmm_kernel(const ushort4* __restrict__ xp,
                                                   const int2* __restrict__ rowinfo,
                                                   const int* __restrict__ csr,
                                                   const float* __restrict__ bias,
                                                   void* __restrict__ yout, int n) {
    int row = blockIdx.x * 4 + (threadIdx.x >> 6);
    if (row >= n) return;
    int lane = threadIdx.x & 63;
    int h = lane >> 4, f = lane & 15;

    int2 ri = rowinfo[row];
    int m = ri.y;
    float is = rsqrtf(1.0f + (float)m);
    const int* eb = csr + ri.x;

    float4 acc = { 0.0f, 0.0f, 0.0f, 0.0f };
    if (h == 0) {                                   // self loop
        ushort4 s = xp[(row << 4) + f];
        acc.x = bf2f(s.x); acc.y = bf2f(s.y); acc.z = bf2f(s.z); acc.w = bf2f(s.w);
    }

    int j = 0;
    for (; j + 32 <= m; j += 32) {                  // 8 gather insts, 32 edges in flight
        int c0 = eb[j + h],      c1 = eb[j + 4 + h];
        int c2 = eb[j + 8 + h],  c3 = eb[j + 12 + h];
        int c4 = eb[j + 16 + h], c5 = eb[j + 20 + h];
        int c6 = eb[j + 24 + h], c7 = eb[j + 28 + h];
        ushort4 g0 = xp[(c0 << 4) + f];
        ushort4 g1 = xp[(c1 << 4) + f];
        ushort4 g2 = xp[(c2 << 4) + f];
        ushort4 g3 = xp[(c3 << 4) + f];
        ushort4 g4 = xp[(c4 << 4) + f];
        ushort4 g5 = xp[(c5 << 4) + f];
        ushort4 g6 = xp[(c6 << 4) + f];
        ushort4 g7 = xp[(c7 << 4) + f];
        acc.x += bf2f(g0.x); acc.y += bf2f(g0.y); acc.z += bf2f(g0.z); acc.w += bf2f(g0.w);
        acc.x += bf2f(g1.x); acc.y += bf2f(g1.y); acc.z += bf2f(g1.z); acc.w += bf2f(g1.w);
        acc.x += bf2f(g2.x); acc.y += bf2f(g2.y); acc.z += bf2f(g2.z); acc.w += bf2f(g2.w);
        acc.x += bf2f(g3.x); acc.y += bf2f(g3.y); acc.z += bf2f(g3.z); acc.w += bf2f(g3.w);
        acc.x += bf2f(g4.x); acc.y += bf2f(g4.y); acc.z += bf2f(g4.z); acc.w += bf2f(g4.w);
        acc.x += bf2f(g5.x); acc.y += bf2f(g5.y); acc.z += bf2f(g5.z); acc.w += bf2f(g5.w);
        acc.x += bf2f(g6.x); acc.y += bf2f(g6.y); acc.z += bf2f(g6.z); acc.w += bf2f(g6.w);
        acc.x += bf2f(g7.x); acc.y += bf2f(g7.y); acc.z += bf2f(g7.z); acc.w += bf2f(g7.w);
    }
    for (; j + 8 <= m; j += 8) {
        int c0 = eb[j + h], c1 = eb[j + 4 + h];
        ushort4 g0 = xp[(c0 << 4) + f];
        ushort4 g1 = xp[(c1 << 4) + f];
        acc.x += bf2f(g0.x); acc.y += bf2f(g0.y); acc.z += bf2f(g0.z); acc.w += bf2f(g0.w);
        acc.x += bf2f(g1.x); acc.y += bf2f(g1.y); acc.z += bf2f(g1.z); acc.w += bf2f(g1.w);
    }
    for (; j < m; j += 4) {
        if (j + h < m) {
            int c = eb[j + h];
            ushort4 g = xp[(c << 4) + f];
            acc.x += bf2f(g.x); acc.y += bf2f(g.y); acc.z += bf2f(g.z); acc.w += bf2f(g.w);
        }
    }

    acc.x += __shfl_xor(acc.x, 16); acc.y += __shfl_xor(acc.y, 16);
    acc.z += __shfl_xor(acc.z, 16); acc.w += __shfl_xor(acc.w, 16);
    acc.x += __shfl_xor(acc.x, 32); acc.y += __shfl_xor(acc.y, 32);
    acc.z += __shfl_xor(acc.z, 32); acc.w += __shfl_xor(acc.w, 32);

    if (h == 0) {
        if (FINAL) {
            float4 b = *(const float4*)&bias[4 * f];
            float4 o = { acc.x * is + b.x, acc.y * is + b.y,
                         acc.z * is + b.z, acc.w * is + b.w };
            ((float4*)yout)[(row << 4) + f] = o;
        } else {
            float sc = is * is;
            ushort4 o = { f2bf(acc.x * sc), f2bf(acc.y * sc),
                          f2bf(acc.z * sc), f2bf(acc.w * sc) };
            ((ushort4*)yout)[(row << 4) + f] = o;
        }
    }
}

// ---------------- launch ----------------

extern "C" void kernel_launch(void* const* d_in, const int* in_sizes, int n_in,
                              void* d_out, int out_size, void* d_ws, size_t ws_size,
                              hipStream_t stream) {
    const float* X     = (const float*)d_in[0];
    const int*   Aidx  = (const int*)d_in[2];
    const float* W     = (const float*)d_in[3];
    const float* bias  = (const float*)d_in[4];
    float*       out   = (float*)d_out;

    const int n = in_sizes[0] / NFEAT;   // 50000
    const int E = in_sizes[1];           // 1600000
    const int nb = (n + 255) >> 8;       // 196 buckets

    char* ws = (char*)d_ws;
    size_t o = 0;
    auto alloc = [&](size_t bytes) { void* p = ws + o; o += (bytes + 255) & ~(size_t)255; return p; };
    int*  bcur    = (int*) alloc(nb * sizeof(int));
    int*  bpack   = (int*) alloc((size_t)nb * BCAP * sizeof(int));   // 7.2 MB
    int*  csr     = (int*) alloc((size_t)nb * BCAP * sizeof(int));   // 7.2 MB
    int2* rowinfo = (int2*)alloc((size_t)n * sizeof(int2));          // 0.4 MB
    unsigned short* xp = (unsigned short*)alloc((size_t)n * NCLS * sizeof(unsigned short)); // 6.4 MB
    unsigned short* z1 = (unsigned short*)alloc((size_t)n * NCLS * sizeof(unsigned short)); // 6.4 MB

    dim3 blk(256);
    dim3 gB1((E + 256 * T1 - 1) / (256 * T1));   // 391
    dim3 gRow((n + 3) / 4);

    hipMemsetAsync(bcur, 0, nb * sizeof(int), stream);
    bucket_kernel<<<gB1, blk, 0, stream>>>((const int2*)Aidx, bcur, bpack, E);
    csrproj_kernel<<<nb, blk, 0, stream>>>(bcur, bpack, X, W, csr, rowinfo, xp, n);

    spmm_kernel<0><<<gRow, blk, 0, stream>>>((const ushort4*)xp, rowinfo, csr, bias, z1, n);
    spmm_kernel<1><<<gRow, blk, 0, stream>>>((const ushort4*)z1, rowinfo, csr, bias, out, n);
}